// Round 12
// baseline (166.846 us; speedup 1.0000x reference)
//
#include <hip/hip_runtime.h>
#include <math.h>

// Problem constants (from reference)
#define NCH 129
#define BS 8
#define TLEN 64000
#define TILE 256          // frame length
#define WARM 64           // u warm-up steps before frame start
#define NFRM 250          // number of frames
#define NSEQ (NCH * BS)   // 1032 sequences
#define NBK (BS * NFRM)   // 2000 (b,frame) cells
#define KF_EDGE 8         // ceil(NBK/256): edge blocks (channel pair 127,128)
#define KF_MAIN (NBK / 4) // 500 main blocks (4 frame-tiles per 256-thr block)
// Lead for r>=1: 192 ISTEP + 64 WSTEP = 256 samples starting at (r-1)*256.
// r==1: starts at sample 0 -> z EXACT. r>=2: zero-init decay 0.97^256~4.1e-4.
#define GI 48             // ISTEP groups (192 steps)
#define GW 16             // WSTEP groups (64 steps)
#define GMAIN 64          // MSTEP groups (256 steps)
#define MAXSEG 128        // (GI+GW+GMAIN) float4 segments per tile

typedef float f2 __attribute__((ext_vector_type(2)));

__device__ __forceinline__ f2 mk2(float a, float b) { f2 r; r.x = a; r.y = b; return r; }

__device__ __forceinline__ f2 fma2(f2 a, f2 b, f2 c) {
#if __has_builtin(__builtin_elementwise_fma)
    return __builtin_elementwise_fma(a, b, c);
#else
    f2 r; r.x = fmaf(a.x, b.x, c.x); r.y = fmaf(a.y, b.y, c.y); return r;
#endif
}

__device__ __forceinline__ float sigf(float v) {
    return __builtin_amdgcn_rcpf(1.0f + __expf(-v));
}
__device__ __forceinline__ f2 sig2(f2 v) {
    f2 r; r.x = sigf(v.x); r.y = sigf(v.y); return r;
}

// Packed pair-of-chains coefficients.
struct C2 { f2 b0, b1, b2, b3, b4, a1, a2, a3, a4; };

__device__ __forceinline__ C2 load_coef2(const float* __restrict__ B,
                                         const float* __restrict__ A,
                                         int cx, int cy) {
    C2 q;
    q.b0 = mk2(B[cx * 5 + 0], B[cy * 5 + 0]);
    q.b1 = mk2(B[cx * 5 + 1], B[cy * 5 + 1]);
    q.b2 = mk2(B[cx * 5 + 2], B[cy * 5 + 2]);
    q.b3 = mk2(B[cx * 5 + 3], B[cy * 5 + 3]);
    q.b4 = mk2(B[cx * 5 + 4], B[cy * 5 + 4]);
    q.a1 = mk2(A[cx * 5 + 1], A[cy * 5 + 1]);
    q.a2 = mk2(A[cx * 5 + 2], A[cy * 5 + 2]);
    q.a3 = mk2(A[cx * 5 + 3], A[cy * 5 + 3]);
    q.a4 = mk2(A[cx * 5 + 4], A[cy * 5 + 4]);
    return q;
}

__device__ __forceinline__ f2 iir2_step(const C2& q, float x,
                                        f2& z0, f2& z1, f2& z2, f2& z3) {
    f2 xx = mk2(x, x);
    f2 y = fma2(q.b0, xx, z0);
    z0 = fma2(-q.a1, y, fma2(q.b1, xx, z1));
    z1 = fma2(-q.a2, y, fma2(q.b2, xx, z2));
    z2 = fma2(-q.a3, y, fma2(q.b3, xx, z3));
    z3 = fma2(-q.a4, y, q.b4 * xx);
    return y;
}

// step macros for packed chains (coef struct must be named q)
#define ISTEP(xv) { (void)iir2_step(q, (xv), z0, z1, z2, z3); }
#define WSTEP(xv)                                                              \
    { f2 y_ = iir2_step(q, (xv), z0, z1, z2, z3);                              \
      u = fma2(beta2, u, sig2(y_)); }
#define MSTEP(xv)                                                              \
    { f2 y_ = iir2_step(q, (xv), z0, z1, z2, z3);                              \
      u = fma2(beta2, u, sig2(y_));                                            \
      float un_ = __shfl_down(u.x, 1, 64);                                     \
      float y4o_ = fmaxf(u.y - u.x, 0.0f);                                     \
      float y4e_ = fmaxf(pend_un - pend_ub, 0.0f);                             \
      g2 = fma2(alpha2, g2, mk2(y4o_, y4e_));                                  \
      pend_un = un_; pend_ub = u.y; }

// ---------------------------------------------------------------------------
// Fused kernel: one wave per frame-tile (b, r), packed chains {2t, 2t+1}.
//   r == 0 : no lead; frame starts at sample 0 with true zero state (exact).
//   r >= 1 : UNIFORM lead of 256 samples from (r-1)*256: 192 ISTEP (zero
//            state) + 64 WSTEP. For r==1 this starts at sample 0 -> z is
//            EXACT (identical to all prior passing rounds). For r>=2 the
//            zero-init error decays by 0.97^256 ~ 4.1e-4 (slowest pole) by
//            frame start — below the bf16 rounding noise floor (absmax 2.0
//            vs threshold 9.88 with 5x headroom).
// Emits per-frame alpha-fold G and first-sample y4f; kD combines.
// Blocks [0, KF_EDGE): channel pair (127,128) -> ch 128, one item/thread.
// Blocks [KF_EDGE, +KF_MAIN): main, wave w -> tile blk*4+w; lane t runs
// packed chains {2t,2t+1}; shfl consumed one step late (pend pipeline).
// ---------------------------------------------------------------------------
__global__ __launch_bounds__(256, 8) void kF_fused(
        const float* __restrict__ wav, const float* __restrict__ B,
        const float* __restrict__ A, float* __restrict__ G,
        float* __restrict__ y4f, float beta, float alpha) {
    __shared__ float4 xs4[4 * MAXSEG];
    int blk = blockIdx.x;
    const f2 beta2 = mk2(beta, beta);
    const f2 alpha2 = mk2(alpha, alpha);

    if (blk < KF_EDGE) {
        // ---- edge: channel pair (127,128), one (b,r) per thread ----
        int item = blk * 256 + threadIdx.x;
        if (item >= NBK) return;
        int b = item / NFRM;
        int r = item - b * NFRM;
        C2 q = load_coef2(B, A, 127, 128);
        f2 z0 = mk2(0.f, 0.f), z1 = z0, z2 = z0, z3 = z0, u = z0;
        int nIst = (r == 0) ? 0 : 4 * GI;
        int nW   = (r == 0) ? 0 : 4 * GW;
        const float* xg = wav + (size_t)b * TLEN
                        + (size_t)r * TILE - (size_t)(nIst + nW);
        #pragma unroll 2
        for (int j = 0; j < nIst; ++j) ISTEP(xg[j]);
        xg += nIst;
        #pragma unroll 2
        for (int j = 0; j < nW; ++j) WSTEP(xg[j]);
        xg += nW;
        float g4 = 0.f, yfirst = 0.f;
        #pragma unroll 2
        for (int j = 0; j < TILE; ++j) {
            f2 y_ = iir2_step(q, xg[j], z0, z1, z2, z3);
            u = fma2(beta2, u, sig2(y_));
            float y4 = fmaxf(u.y - u.x, 0.0f);   // ch128 - ch127
            if (j == 0) yfirst = y4;
            g4 = fmaf(alpha, g4, y4);
        }
        size_t idx = ((size_t)b * NFRM + r) * NCH + 128;
        G[idx] = g4;
        y4f[idx] = yfirst;
        return;
    }

    // ---- main: wave w handles frame-tile (blk-KF_EDGE)*4 + w ----
    int wave = threadIdx.x >> 6;
    int t = threadIdx.x & 63;                // lane 0..63
    int tile = (blk - KF_EDGE) * 4 + wave;   // b * NFRM + r, < NBK
    int b = tile / NFRM;
    int r = tile - b * NFRM;
    int gi = (r == 0) ? 0 : GI;
    int gw = (r == 0) ? 0 : GW;
    int gbase = gi + gw;
    int n4 = gbase + GMAIN;                  // 64 (r==0) or 128
    const float* xg = wav + (size_t)b * TLEN
                    + (size_t)r * TILE - (size_t)(4 * gbase);
    float4* seg = xs4 + wave * MAXSEG;
    for (int i = t; i < n4; i += 64) seg[i] = ((const float4*)xg)[i];
    __syncthreads();

    int cA = 2 * t, cB = 2 * t + 1;          // chains (cB <= 127)
    C2 q = load_coef2(B, A, cA, cB);
    f2 z0 = mk2(0.f, 0.f), z1 = z0, z2 = z0, z3 = z0, u = z0;
    for (int g = 0; g < gi; ++g) {           // zero-state z lead-in
        float4 xq = seg[g];
        ISTEP(xq.x); ISTEP(xq.y); ISTEP(xq.z); ISTEP(xq.w);
    }
    for (int g = gi; g < gbase; ++g) {       // 64 u warm-up steps
        float4 xq = seg[g];
        WSTEP(xq.x); WSTEP(xq.y); WSTEP(xq.z); WSTEP(xq.w);
    }

    // main 256 steps; pipeline: ge consumes shfl one step late.
    f2 g2;
    float fo, fe, pend_un, pend_ub;
    {   // first group: peel j=0 and j=1
        float4 xq = seg[gbase];
        // j = 0
        f2 y_ = iir2_step(q, xq.x, z0, z1, z2, z3);
        u = fma2(beta2, u, sig2(y_));
        float un_ = __shfl_down(u.x, 1, 64);
        float y4o_ = fmaxf(u.y - u.x, 0.0f);
        fo = y4o_;
        g2 = mk2(y4o_, 0.0f);
        pend_un = un_; pend_ub = u.y;
        // j = 1
        y_ = iir2_step(q, xq.y, z0, z1, z2, z3);
        u = fma2(beta2, u, sig2(y_));
        un_ = __shfl_down(u.x, 1, 64);
        y4o_ = fmaxf(u.y - u.x, 0.0f);
        float y4e_ = fmaxf(pend_un - pend_ub, 0.0f);
        fe = y4e_;                            // y4e at j=0
        g2 = fma2(alpha2, g2, mk2(y4o_, y4e_));
        pend_un = un_; pend_ub = u.y;
        // j = 2, 3
        MSTEP(xq.z); MSTEP(xq.w);
    }
    for (int g = gbase + 1; g < gbase + GMAIN; ++g) {
        float4 xq = seg[g];
        MSTEP(xq.x); MSTEP(xq.y); MSTEP(xq.z); MSTEP(xq.w);
    }
    // tail: apply the last pending ge term
    float y4e_last = fmaxf(pend_un - pend_ub, 0.0f);
    float go = g2.x;
    float ge = fmaf(alpha, g2.y, y4e_last);

    size_t base = ((size_t)b * NFRM + r) * NCH;
    G[base + cB] = go;             // channel 2t+1 (odd 1..127)
    y4f[base + cB] = fo;
    if (t < 63) {
        G[base + cB + 1] = ge;     // channel 2t+2 (even 2..126)
        y4f[base + cB + 1] = fe;
    }
}

// ---------------------------------------------------------------------------
// Kernel D v2: lane-per-CHANNEL serial alpha-scan. One block per batch b;
// thread c in [0, 128] owns sequence (b, c) and scans frames serially:
//   o[k] = alpha * s + y4f[k];  s = aL * s + G[k].
// Loads are wave-coalesced (lane stride 4 B within a G/y4f frame-row) —
// the old Kogge-Stone kD gathered with 2064 B lane stride (64 cache lines
// per instruction) at 1 wave/SIMD, which hid ~45-50 us in every round.
// Next-frame prefetch keeps the L2 latency off the dependent-FMA chain.
// ---------------------------------------------------------------------------
__global__ __launch_bounds__(256) void kD_scan_seq(
        const float* __restrict__ G, const float* __restrict__ y4f,
        float* __restrict__ out, float alpha, float aL) {
    int b = blockIdx.x;
    int c = threadIdx.x;
    if (c > 128) return;
    float* o = out + ((size_t)b * NCH + c) * NFRM;
    if (c == 0) {
        for (int k = 0; k < NFRM; ++k) o[k] = 0.0f;   // channel 0 is zero
        return;
    }
    const float* gp = G + (size_t)b * NFRM * NCH + c;
    const float* yp = y4f + (size_t)b * NFRM * NCH + c;
    float s = 0.f;
    float g = gp[0], y = yp[0];
    #pragma unroll 2
    for (int k = 0; k < NFRM; ++k) {
        float gn = 0.f, yn = 0.f;
        if (k + 1 < NFRM) {                  // prefetch next frame row
            gn = gp[(size_t)(k + 1) * NCH];
            yn = yp[(size_t)(k + 1) * NCH];
        }
        o[k] = fmaf(alpha, s, y);
        s = fmaf(aL, s, g);
        g = gn; y = yn;
    }
}

// ---------------------------------------------------------------------------
extern "C" void kernel_launch(void* const* d_in, const int* in_sizes, int n_in,
                              void* d_out, int out_size, void* d_ws, size_t ws_size,
                              hipStream_t stream) {
    const float* wav = (const float*)d_in[0];   // (BS, TLEN)
    const float* Bc  = (const float*)d_in[1];   // (NCH, 5)
    const float* Ac  = (const float*)d_in[2];   // (NCH, 5)
    float* out = (float*)d_out;                 // (BS, NCH, NFRM)

    // workspace (floats): G | y4f (1.03 MB each)
    float* G   = (float*)d_ws;
    float* y4f = G + (size_t)NBK * NCH;

    const float alpha  = (float)exp(-1.0 / 128.0);
    const float beta   = (float)exp(-1.0 / 8.0);
    const float alphaL = (float)exp(-256.0 / 128.0);   // alpha^256 (frame step)

    kF_fused<<<KF_EDGE + KF_MAIN, 256, 0, stream>>>(wav, Bc, Ac, G, y4f, beta, alpha);
    kD_scan_seq<<<BS, 256, 0, stream>>>(G, y4f, out, alpha, alphaL);
}

// Round 13
// 110.070 us; speedup vs baseline: 1.5158x; 1.5158x over previous
//
#include <hip/hip_runtime.h>
#include <math.h>

// Problem constants (from reference)
#define NCH 129
#define BS 8
#define TLEN 64000
#define TILE 256          // frame length
#define WARM 64           // u warm-up steps before frame start
#define NFRM 250          // number of frames
#define NSEQ (NCH * BS)   // 1032 sequences
#define NBK (BS * NFRM)   // 2000 (b,frame) cells
#define KF_EDGE 8         // ceil(NBK/256): edge blocks (channel pair 127,128)
#define KF_MAIN (NBK / 4) // 500 main blocks (4 frame-tiles per 256-thr block)
// Lead for r>=1: 128 ISTEP + 64 WSTEP = 192 samples starting at r*256-192.
// Zero-init decay by frame start: 0.97^192 ~ 2.9e-3 (slowest pole) — at the
// bf16 rounding level that dominates absmax (R12: 320->256 trim left absmax
// identical at 2.0).
#define GI 32             // ISTEP groups (128 steps)
#define GW 16             // WSTEP groups (64 steps)
#define GMAIN 64          // MSTEP groups (256 steps)
#define MAXSEG 112        // (GI+GW+GMAIN) float4 segments per tile

typedef float f2 __attribute__((ext_vector_type(2)));

__device__ __forceinline__ f2 mk2(float a, float b) { f2 r; r.x = a; r.y = b; return r; }

__device__ __forceinline__ f2 fma2(f2 a, f2 b, f2 c) {
#if __has_builtin(__builtin_elementwise_fma)
    return __builtin_elementwise_fma(a, b, c);
#else
    f2 r; r.x = fmaf(a.x, b.x, c.x); r.y = fmaf(a.y, b.y, c.y); return r;
#endif
}

__device__ __forceinline__ float sigf(float v) {
    return __builtin_amdgcn_rcpf(1.0f + __expf(-v));
}
__device__ __forceinline__ f2 sig2(f2 v) {
    f2 r; r.x = sigf(v.x); r.y = sigf(v.y); return r;
}

// Packed pair-of-chains coefficients.
struct C2 { f2 b0, b1, b2, b3, b4, a1, a2, a3, a4; };

__device__ __forceinline__ C2 load_coef2(const float* __restrict__ B,
                                         const float* __restrict__ A,
                                         int cx, int cy) {
    C2 q;
    q.b0 = mk2(B[cx * 5 + 0], B[cy * 5 + 0]);
    q.b1 = mk2(B[cx * 5 + 1], B[cy * 5 + 1]);
    q.b2 = mk2(B[cx * 5 + 2], B[cy * 5 + 2]);
    q.b3 = mk2(B[cx * 5 + 3], B[cy * 5 + 3]);
    q.b4 = mk2(B[cx * 5 + 4], B[cy * 5 + 4]);
    q.a1 = mk2(A[cx * 5 + 1], A[cy * 5 + 1]);
    q.a2 = mk2(A[cx * 5 + 2], A[cy * 5 + 2]);
    q.a3 = mk2(A[cx * 5 + 3], A[cy * 5 + 3]);
    q.a4 = mk2(A[cx * 5 + 4], A[cy * 5 + 4]);
    return q;
}

__device__ __forceinline__ f2 iir2_step(const C2& q, float x,
                                        f2& z0, f2& z1, f2& z2, f2& z3) {
    f2 xx = mk2(x, x);
    f2 y = fma2(q.b0, xx, z0);
    z0 = fma2(-q.a1, y, fma2(q.b1, xx, z1));
    z1 = fma2(-q.a2, y, fma2(q.b2, xx, z2));
    z2 = fma2(-q.a3, y, fma2(q.b3, xx, z3));
    z3 = fma2(-q.a4, y, q.b4 * xx);
    return y;
}

// step macros for packed chains (coef struct must be named q)
#define ISTEP(xv) { (void)iir2_step(q, (xv), z0, z1, z2, z3); }
#define WSTEP(xv)                                                              \
    { f2 y_ = iir2_step(q, (xv), z0, z1, z2, z3);                              \
      u = fma2(beta2, u, sig2(y_)); }
#define MSTEP(xv)                                                              \
    { f2 y_ = iir2_step(q, (xv), z0, z1, z2, z3);                              \
      u = fma2(beta2, u, sig2(y_));                                            \
      float un_ = __shfl_down(u.x, 1, 64);                                     \
      float y4o_ = fmaxf(u.y - u.x, 0.0f);                                     \
      float y4e_ = fmaxf(pend_un - pend_ub, 0.0f);                             \
      g2 = fma2(alpha2, g2, mk2(y4o_, y4e_));                                  \
      pend_un = un_; pend_ub = u.y; }

// ---------------------------------------------------------------------------
// Fused kernel: one wave per frame-tile (b, r), packed chains {2t, 2t+1}.
//   r == 0 : no lead; frame starts at sample 0 with true zero state (exact).
//   r >= 1 : UNIFORM lead of 192 samples from r*256-192: 128 ISTEP (zero
//            state) + 64 WSTEP. Zero-init error decays by 0.97^192 ~ 2.9e-3
//            by frame start — below the bf16 rounding noise floor.
// Emits per-frame alpha-fold G and first-sample y4f; kD combines.
// Blocks [0, KF_EDGE): channel pair (127,128) -> ch 128, one item/thread.
// Blocks [KF_EDGE, +KF_MAIN): main, wave w -> tile blk*4+w; lane t runs
// packed chains {2t,2t+1}; shfl consumed one step late (pend pipeline).
// ---------------------------------------------------------------------------
__global__ __launch_bounds__(256, 8) void kF_fused(
        const float* __restrict__ wav, const float* __restrict__ B,
        const float* __restrict__ A, float* __restrict__ G,
        float* __restrict__ y4f, float beta, float alpha) {
    __shared__ float4 xs4[4 * MAXSEG];
    int blk = blockIdx.x;
    const f2 beta2 = mk2(beta, beta);
    const f2 alpha2 = mk2(alpha, alpha);

    if (blk < KF_EDGE) {
        // ---- edge: channel pair (127,128), one (b,r) per thread ----
        int item = blk * 256 + threadIdx.x;
        if (item >= NBK) return;
        int b = item / NFRM;
        int r = item - b * NFRM;
        C2 q = load_coef2(B, A, 127, 128);
        f2 z0 = mk2(0.f, 0.f), z1 = z0, z2 = z0, z3 = z0, u = z0;
        int nIst = (r == 0) ? 0 : 4 * GI;
        int nW   = (r == 0) ? 0 : 4 * GW;
        const float* xg = wav + (size_t)b * TLEN
                        + (size_t)r * TILE - (size_t)(nIst + nW);
        #pragma unroll 2
        for (int j = 0; j < nIst; ++j) ISTEP(xg[j]);
        xg += nIst;
        #pragma unroll 2
        for (int j = 0; j < nW; ++j) WSTEP(xg[j]);
        xg += nW;
        float g4 = 0.f, yfirst = 0.f;
        #pragma unroll 2
        for (int j = 0; j < TILE; ++j) {
            f2 y_ = iir2_step(q, xg[j], z0, z1, z2, z3);
            u = fma2(beta2, u, sig2(y_));
            float y4 = fmaxf(u.y - u.x, 0.0f);   // ch128 - ch127
            if (j == 0) yfirst = y4;
            g4 = fmaf(alpha, g4, y4);
        }
        size_t idx = ((size_t)b * NFRM + r) * NCH + 128;
        G[idx] = g4;
        y4f[idx] = yfirst;
        return;
    }

    // ---- main: wave w handles frame-tile (blk-KF_EDGE)*4 + w ----
    int wave = threadIdx.x >> 6;
    int t = threadIdx.x & 63;                // lane 0..63
    int tile = (blk - KF_EDGE) * 4 + wave;   // b * NFRM + r, < NBK
    int b = tile / NFRM;
    int r = tile - b * NFRM;
    int gi = (r == 0) ? 0 : GI;
    int gw = (r == 0) ? 0 : GW;
    int gbase = gi + gw;
    int n4 = gbase + GMAIN;                  // 64 (r==0) or 112
    const float* xg = wav + (size_t)b * TLEN
                    + (size_t)r * TILE - (size_t)(4 * gbase);
    float4* seg = xs4 + wave * MAXSEG;
    for (int i = t; i < n4; i += 64) seg[i] = ((const float4*)xg)[i];
    __syncthreads();

    int cA = 2 * t, cB = 2 * t + 1;          // chains (cB <= 127)
    C2 q = load_coef2(B, A, cA, cB);
    f2 z0 = mk2(0.f, 0.f), z1 = z0, z2 = z0, z3 = z0, u = z0;
    for (int g = 0; g < gi; ++g) {           // zero-state z lead-in
        float4 xq = seg[g];
        ISTEP(xq.x); ISTEP(xq.y); ISTEP(xq.z); ISTEP(xq.w);
    }
    for (int g = gi; g < gbase; ++g) {       // 64 u warm-up steps
        float4 xq = seg[g];
        WSTEP(xq.x); WSTEP(xq.y); WSTEP(xq.z); WSTEP(xq.w);
    }

    // main 256 steps; pipeline: ge consumes shfl one step late.
    f2 g2;
    float fo, fe, pend_un, pend_ub;
    {   // first group: peel j=0 and j=1
        float4 xq = seg[gbase];
        // j = 0
        f2 y_ = iir2_step(q, xq.x, z0, z1, z2, z3);
        u = fma2(beta2, u, sig2(y_));
        float un_ = __shfl_down(u.x, 1, 64);
        float y4o_ = fmaxf(u.y - u.x, 0.0f);
        fo = y4o_;
        g2 = mk2(y4o_, 0.0f);
        pend_un = un_; pend_ub = u.y;
        // j = 1
        y_ = iir2_step(q, xq.y, z0, z1, z2, z3);
        u = fma2(beta2, u, sig2(y_));
        un_ = __shfl_down(u.x, 1, 64);
        y4o_ = fmaxf(u.y - u.x, 0.0f);
        float y4e_ = fmaxf(pend_un - pend_ub, 0.0f);
        fe = y4e_;                            // y4e at j=0
        g2 = fma2(alpha2, g2, mk2(y4o_, y4e_));
        pend_un = un_; pend_ub = u.y;
        // j = 2, 3
        MSTEP(xq.z); MSTEP(xq.w);
    }
    for (int g = gbase + 1; g < gbase + GMAIN; ++g) {
        float4 xq = seg[g];
        MSTEP(xq.x); MSTEP(xq.y); MSTEP(xq.z); MSTEP(xq.w);
    }
    // tail: apply the last pending ge term
    float y4e_last = fmaxf(pend_un - pend_ub, 0.0f);
    float go = g2.x;
    float ge = fmaf(alpha, g2.y, y4e_last);

    size_t base = ((size_t)b * NFRM + r) * NCH;
    G[base + cB] = go;             // channel 2t+1 (odd 1..127)
    y4f[base + cB] = fo;
    if (t < 63) {
        G[base + cB + 1] = ge;     // channel 2t+2 (even 2..126)
        y4f[base + cB + 1] = fe;
    }
}

// ---------------------------------------------------------------------------
// Kernel D (REVERTED to R11 Kogge-Stone): one wave per sequence (b,c);
// lane l owns frames [4l, 4l+4). Stores are coalesced (4 consecutive
// frames per lane); scattered loads are hidden by 1032 waves of TLP.
// R12's 8-block serial variant regressed ~52 us (16 waves total on 256 CUs
// + 1000 B-stride scatter stores) — parallelism + store coalescing win.
//   o[k] = alpha * s_in[k] + y4f[k];  s' = aL*s + G[k].
// ---------------------------------------------------------------------------
#define KD_LOAD(gn, yn, i)                                                     \
    {   int kk = k0 + (i); int kcl = (kk < NFRM) ? kk : (NFRM - 1);            \
        size_t ix = ((size_t)b * NFRM + kcl) * NCH + c;                        \
        gn = G[ix]; yn = y4f[ix];                                              \
        if (kk >= NFRM) { gn = 0.f; yn = 0.f; } }
#define KD_REPLAY(gn, yn, i)                                                   \
    {   int kk = k0 + (i);                                                     \
        if (kk < NFRM) o[kk] = fmaf(alpha, sv, yn);                            \
        sv = fmaf(aL, sv, gn); }

__global__ __launch_bounds__(256) void kD_scan_par(
        const float* __restrict__ G, const float* __restrict__ y4f,
        float* __restrict__ out, float alpha, float aL) {
    int id = blockIdx.x * 4 + (threadIdx.x >> 6);   // b * NCH + c
    int lane = threadIdx.x & 63;
    if (id >= NSEQ) return;
    int b = id / NCH;
    int c = id - b * NCH;
    float* o = out + (size_t)id * NFRM;
    int k0 = lane * 4;
    if (c == 0) {
        #pragma unroll
        for (int i = 0; i < 4; ++i) {
            int kk = k0 + i;
            if (kk < NFRM) o[kk] = 0.0f;
        }
        return;
    }
    float g0, g1, g2v, g3, y0, y1, y2v, y3;
    KD_LOAD(g0, y0, 0); KD_LOAD(g1, y1, 1); KD_LOAD(g2v, y2v, 2); KD_LOAD(g3, y3, 3);
    // local inclusive carry
    float e = g0;
    e = fmaf(aL, e, g1);
    e = fmaf(aL, e, g2v);
    e = fmaf(aL, e, g3);
    // Kogge-Stone with factor f = (aL^4)^{2^s}
    float aL2 = aL * aL;
    float f = aL2 * aL2;                     // aL^4
    for (int s = 0; s < 6; ++s) {
        int off = 1 << s;
        float src = __shfl_up(e, off, 64);
        if (lane < off) src = 0.f;
        e = fmaf(f, src, e);
        f = f * f;
    }
    // exclusive shift
    float sv = __shfl_up(e, 1, 64);
    if (lane == 0) sv = 0.f;
    // replay + store
    KD_REPLAY(g0, y0, 0); KD_REPLAY(g1, y1, 1);
    KD_REPLAY(g2v, y2v, 2); KD_REPLAY(g3, y3, 3);
}

// ---------------------------------------------------------------------------
extern "C" void kernel_launch(void* const* d_in, const int* in_sizes, int n_in,
                              void* d_out, int out_size, void* d_ws, size_t ws_size,
                              hipStream_t stream) {
    const float* wav = (const float*)d_in[0];   // (BS, TLEN)
    const float* Bc  = (const float*)d_in[1];   // (NCH, 5)
    const float* Ac  = (const float*)d_in[2];   // (NCH, 5)
    float* out = (float*)d_out;                 // (BS, NCH, NFRM)

    // workspace (floats): G | y4f (1.03 MB each)
    float* G   = (float*)d_ws;
    float* y4f = G + (size_t)NBK * NCH;

    const float alpha  = (float)exp(-1.0 / 128.0);
    const float beta   = (float)exp(-1.0 / 8.0);
    const float alphaL = (float)exp(-256.0 / 128.0);   // alpha^256 (frame step)

    kF_fused<<<KF_EDGE + KF_MAIN, 256, 0, stream>>>(wav, Bc, Ac, G, y4f, beta, alpha);
    kD_scan_par<<<NSEQ / 4, 256, 0, stream>>>(G, y4f, out, alpha, alphaL);
}